// Round 2
// baseline (332.490 us; speedup 1.0000x reference)
//
#include <hip/hip_runtime.h>
#include <math.h>

#define B_   128
#define R_   1152
#define C_   16
#define O_   16
#define RS_  128
#define RCH_ 9             // R_/RS_
#define NBLK 1024
#define NFIN 128

// ws float offsets
#define WS_SP   0          // RS_*B_*256 = 4194304
#define WS_V    4194304    // 32768
#define WS_BLOG 4227072    // 18432
#define WS_CTRL 4245504    // 64 words: [0..2] uint ctrs, [16..31] colsum0, [32..47] colsum1
#define WS_WT   4245568    // 2359296 (Wt4[r*512 + d*64 + co4])

__device__ __forceinline__ float squashf(float s) {
    return s * fabsf(s) / (1.0f + s * s);
}

// ---------- T: Wt4[r*512 + d*64 + co4] = W4[r*512 + co*2 + d]  (pitch-65 LDS swizzle)
//             + zero the control words (ctrs + colsums) once per run
__global__ __launch_bounds__(512) void wtrans_k(const float* __restrict__ W,
                                                float* __restrict__ wt,
                                                float* __restrict__ ctrl) {
    const int r = blockIdx.x;
    const int t = threadIdx.x;
    __shared__ float4 sh[520];
    const float4* __restrict__ W4 = (const float4*)W;
    float4* __restrict__ Wt4 = (float4*)wt;

    if (r == 0 && t < 64) ctrl[t] = 0.0f;

    sh[(t & 7) * 65 + (t >> 3)] = W4[r * 512 + t];     // t = co4*8 + d
    __syncthreads();
    Wt4[r * 512 + t] = sh[(t >> 6) * 65 + (t & 63)];   // t = d*64 + co4
}

// ---------- G: sp[rs][b][co] = sum_{r in chunk,i} x[b,r,i]*cw[r,c]*W[r,co,i]
// grid 1024 x 256, 4 blocks/CU. XCD-swizzled: bid%8 -> 16-chunk rs-group per XCD
// (Wt slice 1.2 MB L2-resident). launch_bounds(256,2): VGPR cap 256 so the
// software-pipelined W double-buffer stays in registers (round-1 spilled at 64).
// Last NFIN arriving blocks reduce the 128 k-slices, squash, write dst (v or out).
template <bool FIRST>
__global__ __launch_bounds__(256, 2) void gemm_s_k(const float* __restrict__ x,
                                                   const float* __restrict__ wt,
                                                   const float* __restrict__ blog,
                                                   const float* __restrict__ colsum,
                                                   float* __restrict__ sp,
                                                   float* __restrict__ dst,
                                                   unsigned int* __restrict__ ctr) {
    const int bid = blockIdx.x;
    const int xcd = bid & 7;
    const int g   = bid >> 3;                 // 0..127
    const int rs  = xcd * 16 + (g & 15);      // XCD owns rs in [16*xcd, 16*xcd+16)
    const int bt  = g >> 4;                   // 0..7
    const int t   = threadIdx.x;
    const int co4 = t & 63;
    const int b4  = t >> 6;
    const int c   = co4 >> 2;
    const int r0  = rs * RCH_;

    __shared__ float4 xl4[16 * RCH_ * 2];     // 288 f4 = 4.6 KB
    __shared__ float  cwl[RCH_ * 16];         // 144
    __shared__ float  colinv_sh[16];
    __shared__ float4 red[256];               // finisher reduction (4 KB)
    __shared__ unsigned int old_sh;

    const float4* __restrict__ X4  = (const float4*)x;
    const float4* __restrict__ Wt4 = (const float4*)wt;

    // stage x tile: 16 b x 9 r x 2 f4
    #pragma unroll
    for (int k = 0; k < 2; ++k) {
        const int u = t + k * 256;
        if (u < 16 * RCH_ * 2) {
            const int bl = u / (RCH_ * 2), rem = u % (RCH_ * 2);
            xl4[u] = X4[((bt * 16 + bl) * R_ + r0) * 2 + rem];
        }
    }

    // cheap prepass: cwl[rl][cc] = exp(blog)*1/colsum (colsum built by previous a_k)
    if (!FIRST) {
        if (t < 16) colinv_sh[t] = 1.0f / colsum[t];
        __syncthreads();
        if (t < RCH_ * 16) {
            const int rl = t >> 4, cc = t & 15;
            cwl[t] = __expf(blog[(r0 + rl) * 16 + cc]) * colinv_sh[cc];
        }
    }
    __syncthreads();

    float acc[4][4];
    #pragma unroll
    for (int j = 0; j < 4; ++j)
        #pragma unroll
        for (int q = 0; q < 4; ++q) acc[j][q] = 0.f;

    const float4* __restrict__ wbase = Wt4 + ((size_t)r0 << 9) + co4;

    auto body = [&](int rr, const float4* wv) {
        const float cwv = FIRST ? (1.0f / (float)R_) : cwl[rr * 16 + c];
        #pragma unroll
        for (int j = 0; j < 4; ++j) {
            const float4 xa = xl4[(b4 * 4 + j) * (RCH_ * 2) + rr * 2];
            const float4 xb = xl4[(b4 * 4 + j) * (RCH_ * 2) + rr * 2 + 1];
            const float d0 = wv[0].x*xa.x + wv[0].y*xa.y + wv[0].z*xa.z + wv[0].w*xa.w
                           + wv[1].x*xb.x + wv[1].y*xb.y + wv[1].z*xb.z + wv[1].w*xb.w;
            const float d1 = wv[2].x*xa.x + wv[2].y*xa.y + wv[2].z*xa.z + wv[2].w*xa.w
                           + wv[3].x*xb.x + wv[3].y*xb.y + wv[3].z*xb.z + wv[3].w*xb.w;
            const float d2 = wv[4].x*xa.x + wv[4].y*xa.y + wv[4].z*xa.z + wv[4].w*xa.w
                           + wv[5].x*xb.x + wv[5].y*xb.y + wv[5].z*xb.z + wv[5].w*xb.w;
            const float d3 = wv[6].x*xa.x + wv[6].y*xa.y + wv[6].z*xa.z + wv[6].w*xa.w
                           + wv[7].x*xb.x + wv[7].y*xb.y + wv[7].z*xb.z + wv[7].w*xb.w;
            acc[j][0] = fmaf(cwv, d0, acc[j][0]);
            acc[j][1] = fmaf(cwv, d1, acc[j][1]);
            acc[j][2] = fmaf(cwv, d2, acc[j][2]);
            acc[j][3] = fmaf(cwv, d3, acc[j][3]);
        }
    };

    // software-pipelined K loop: prefetch next rr's 8 W-fragments into regs
    float4 w[8];
    #pragma unroll
    for (int q = 0; q < 8; ++q) w[q] = wbase[q * 64];
    for (int rr = 0; rr < RCH_ - 1; ++rr) {
        float4 wn[8];
        const float4* wp = wbase + ((size_t)(rr + 1) << 9);
        #pragma unroll
        for (int q = 0; q < 8; ++q) wn[q] = wp[q * 64];
        body(rr, w);
        #pragma unroll
        for (int q = 0; q < 8; ++q) w[q] = wn[q];
    }
    body(RCH_ - 1, w);

    // write partials
    float4* sp4 = (float4*)sp;
    #pragma unroll
    for (int j = 0; j < 4; ++j) {
        const int b = bt * 16 + b4 * 4 + j;
        float4 o4; o4.x = acc[j][0]; o4.y = acc[j][1]; o4.z = acc[j][2]; o4.w = acc[j][3];
        sp4[(rs * B_ + b) * 64 + co4] = o4;
    }

    // ---- fused reduce+squash: last NFIN arrivals finish ----
    __syncthreads();                       // drains all waves' stores (vmcnt 0 before barrier)
    if (t == 0) {
        __threadfence();                   // release: L2 writeback, device scope
        old_sh = atomicAdd(ctr, 1u);
    }
    __syncthreads();
    const unsigned int old = old_sh;
    if (old < (unsigned int)(NBLK - NFIN)) return;
    const int fid = (int)old - (NBLK - NFIN);   // 0..NFIN-1 -> batch index

    if (t == 0) {
        while (__hip_atomic_load(ctr, __ATOMIC_RELAXED, __HIP_MEMORY_SCOPE_AGENT)
               < (unsigned int)NBLK) {
            __builtin_amdgcn_s_sleep(2);
        }
    }
    __syncthreads();
    __threadfence();                       // acquire: invalidate caches before cross-XCD reads

    const int li = t & 63, kq = t >> 6;    // 4-way k split over 128 slices
    const int out4 = fid * 64 + li;        // f4 index into v [128 b][64 co4]
    const float4* __restrict__ sp4c = (const float4*)sp;
    float4 a; a.x = 0.f; a.y = 0.f; a.z = 0.f; a.w = 0.f;
    #pragma unroll 8
    for (int k = 0; k < 32; ++k) {
        const float4 u = sp4c[(size_t)(kq * 32 + k) * (B_ * 64) + out4];
        a.x += u.x; a.y += u.y; a.z += u.z; a.w += u.w;
    }
    red[t] = a;
    __syncthreads();
    if (t < 64) {
        const float4 p0 = red[t], p1 = red[t + 64], p2 = red[t + 128], p3 = red[t + 192];
        float4 o;
        o.x = squashf((p0.x + p1.x) + (p2.x + p3.x));
        o.y = squashf((p0.y + p1.y) + (p2.y + p3.y));
        o.z = squashf((p0.z + p1.z) + (p2.z + p3.z));
        o.w = squashf((p0.w + p1.w) + (p2.w + p3.w));
        ((float4*)dst)[fid * 64 + t] = o;
    }
}

// ---------- A: blog[r,c] (+)= (1/B) sum_{b,o} u_hat[b,r,co]*v[b,co]
// grid 1152 x 256 (1 r per block, 4 waves = batch quarters). Also accumulates
// colsum[c] += exp(new_blog) via float atomics for the next gemm's softmax.
template <bool FIRST>
__global__ __launch_bounds__(256, 4) void a_k(const float* __restrict__ x,
                                              const float* __restrict__ wt,
                                              const float* __restrict__ v,
                                              float* __restrict__ blog,
                                              float* __restrict__ colsum) {
    const int r = blockIdx.x;
    const int t = threadIdx.x;
    const int w = t >> 6, lane = t & 63;
    const int co4 = lane, c = lane >> 2;

    __shared__ float4 xl[256];            // 128 b x 2 f4 = 4 KB
    __shared__ float  red[64];
    const float4* __restrict__ X4  = (const float4*)x;
    const float4* __restrict__ V4  = (const float4*)v;
    const float4* __restrict__ Wt4 = (const float4*)wt;

    {
        const int b = t >> 1, rem = t & 1;
        xl[t] = X4[(b * R_ + r) * 2 + rem];
    }
    __syncthreads();

    float y[8][4];
    #pragma unroll
    for (int i = 0; i < 8; ++i)
        #pragma unroll
        for (int q = 0; q < 4; ++q) y[i][q] = 0.f;

    const int b0 = w * 32;
    #pragma unroll 4
    for (int bb = 0; bb < 32; ++bb) {
        const int b = b0 + bb;
        const float4 xa = xl[b * 2];
        const float4 xb = xl[b * 2 + 1];
        const float4 vv = V4[b * 64 + co4];
        const float xs[8] = {xa.x, xa.y, xa.z, xa.w, xb.x, xb.y, xb.z, xb.w};
        #pragma unroll
        for (int i = 0; i < 8; ++i) {
            y[i][0] = fmaf(xs[i], vv.x, y[i][0]);
            y[i][1] = fmaf(xs[i], vv.y, y[i][1]);
            y[i][2] = fmaf(xs[i], vv.z, y[i][2]);
            y[i][3] = fmaf(xs[i], vv.w, y[i][3]);
        }
    }

    const float4* wp = Wt4 + ((size_t)r << 9) + co4;
    float part = 0.f;
    #pragma unroll
    for (int q = 0; q < 4; ++q) {
        const float4 w0 = wp[(2 * q) * 64];
        const float4 w1 = wp[(2 * q + 1) * 64];
        part += w0.x*y[0][q] + w0.y*y[1][q] + w0.z*y[2][q] + w0.w*y[3][q]
              + w1.x*y[4][q] + w1.y*y[5][q] + w1.z*y[6][q] + w1.w*y[7][q];
    }
    part += __shfl_xor(part, 1);
    part += __shfl_xor(part, 2);
    if ((lane & 3) == 0) red[w * 16 + c] = part;
    __syncthreads();
    if (t < 16) {
        const float val = ((red[t] + red[16 + t]) + (red[32 + t] + red[48 + t]))
                          * (1.0f / (float)B_);
        const int idx = r * 16 + t;
        const float nv = FIRST ? val : (blog[idx] + val);
        blog[idx] = nv;
        atomicAdd(&colsum[t], __expf(nv));   // softmax denominator for next gemm
    }
}

extern "C" void kernel_launch(void* const* d_in, const int* in_sizes, int n_in,
                              void* d_out, int out_size, void* d_ws, size_t ws_size,
                              hipStream_t stream) {
    const float* x = (const float*)d_in[0];   // [128,1152,8]
    const float* W = (const float*)d_in[1];   // [1,1152,16,16,8]
    float* out = (float*)d_out;               // [128,16,16]
    float* ws  = (float*)d_ws;                // ~26.4 MB used

    float* sp   = ws + WS_SP;
    float* v    = ws + WS_V;
    float* blog = ws + WS_BLOG;
    float* ctrl = ws + WS_CTRL;
    float* wt   = ws + WS_WT;

    unsigned int* ctr = (unsigned int*)ctrl;  // [0],[1],[2]
    float* cs0 = ctrl + 16;
    float* cs1 = ctrl + 32;

    // build Wt once (coalesced transpose) + zero counters/colsums
    wtrans_k<<<R_, 512, 0, stream>>>(W, wt, ctrl);

    // iter 0 (softmax(0) == 1/R exactly); gemm finishes v internally
    gemm_s_k<true ><<<NBLK, 256, 0, stream>>>(x, wt, nullptr, nullptr, sp, v, ctr + 0);
    a_k<true ><<<R_, 256, 0, stream>>>(x, wt, v, blog, cs0);

    // iter 1
    gemm_s_k<false><<<NBLK, 256, 0, stream>>>(x, wt, blog, cs0, sp, v, ctr + 1);
    a_k<false><<<R_, 256, 0, stream>>>(x, wt, v, blog, cs1);

    // iter 2 — finishers write squash(s) directly to out
    gemm_s_k<false><<<NBLK, 256, 0, stream>>>(x, wt, blog, cs1, sp, out, ctr + 2);
}

// Round 3
// 206.390 us; speedup vs baseline: 1.6110x; 1.6110x over previous
//
#include <hip/hip_runtime.h>
#include <math.h>

#define B_   128
#define R_   1152
#define C_   16
#define O_   16
#define RS_  96
#define RCH_ 12            // R_/RS_
#define NBLK 768           // 8 bt x 96 rs
#define SLICE_P 8464       // f4 per k-slice: 8192 + 272 pad (132.25 KB, non-pow2 -> channel spread)

// ws float offsets
#define WS_SP   0          // RS_*SLICE_P*4 = 3250176
#define WS_V    3250176    // 32768
#define WS_BLOG 3282944    // 18432
#define WS_CTRL 3301376    // 768 floats: cs0 at +256 (stride 16), cs1 at +512 (stride 16)
#define WS_WT   3302144    // 2359296 (Wt4[r*512 + d*64 + co4])

__device__ __forceinline__ float squashf(float s) {
    return s * fabsf(s) / (1.0f + s * s);
}

// ---------- T: Wt4[r*512 + d*64 + co4] = W4[r*512 + co4*8 + d]  (pitch-65 LDS swizzle)
//             + zero the colsum control area once per run
__global__ __launch_bounds__(512) void wtrans_k(const float* __restrict__ W,
                                                float* __restrict__ wt,
                                                float* __restrict__ ctrl) {
    const int r = blockIdx.x;
    const int t = threadIdx.x;
    __shared__ float4 sh[520];
    const float4* __restrict__ W4 = (const float4*)W;
    float4* __restrict__ Wt4 = (float4*)wt;

    if (r == 0) {
        for (int u = t; u < 768; u += 512) ctrl[u] = 0.0f;
    }

    sh[(t & 7) * 65 + (t >> 3)] = W4[r * 512 + t];     // t = co4*8 + d
    __syncthreads();
    Wt4[r * 512 + t] = sh[(t >> 6) * 65 + (t & 63)];   // t = d*64 + co4
}

// ---------- G: sp[rs][b][co] = sum_{r in chunk,i} x[b,r,i]*cw[r,c]*W[r,co,i]
// grid 768 x 256 (3 blocks/CU). XCD-swizzled: bid%8 -> 12-chunk rs-group per XCD
// (Wt slice 1.2 MB + x slice 0.6 MB L2-resident per XCD).
// sp k-slices at non-pow2 pitch SLICE_P so the reduce's k-walk rotates HBM channels.
template <bool FIRST>
__global__ __launch_bounds__(256) void gemm_s_k(const float* __restrict__ x,
                                                const float* __restrict__ wt,
                                                const float* __restrict__ blog,
                                                const float* __restrict__ colsum,
                                                float* __restrict__ sp) {
    const int bid = blockIdx.x;
    const int xcd = bid & 7;
    const int g   = bid >> 3;                 // 0..95
    const int rs  = xcd * 12 + g % 12;        // XCD owns rs in [12*xcd, 12*xcd+12)
    const int bt  = g / 12;                   // 0..7
    const int t   = threadIdx.x;
    const int co4 = t & 63;
    const int b4  = t >> 6;
    const int c   = co4 >> 2;
    const int r0  = rs * RCH_;

    __shared__ float4 xl4[16 * RCH_ * 2];     // 384 f4 = 6 KB
    __shared__ float  cwl[RCH_ * 16];         // 192
    __shared__ float  colinv_sh[16];

    const float4* __restrict__ X4  = (const float4*)x;
    const float4* __restrict__ Wt4 = (const float4*)wt;

    // stage x tile: 16 b x 12 r x 2 f4
    #pragma unroll
    for (int k = 0; k < 2; ++k) {
        const int u = t + k * 256;
        if (u < 16 * RCH_ * 2) {
            const int bl = u / (RCH_ * 2), rem = u % (RCH_ * 2);
            xl4[u] = X4[((bt * 16 + bl) * R_ + r0) * 2 + rem];
        }
    }

    // cheap prepass: cwl[rl][cc] = exp(blog)*1/colsum (colsum built by previous a_k)
    if (!FIRST) {
        if (t < 16) colinv_sh[t] = 1.0f / colsum[t * 16];
        __syncthreads();
        if (t < RCH_ * 16) {
            const int rl = t >> 4, cc = t & 15;
            cwl[t] = __expf(blog[(r0 + rl) * 16 + cc]) * colinv_sh[cc];
        }
    }
    __syncthreads();

    float acc[4][4];
    #pragma unroll
    for (int j = 0; j < 4; ++j)
        #pragma unroll
        for (int q = 0; q < 4; ++q) acc[j][q] = 0.f;

    const float4* __restrict__ wbase = Wt4 + ((size_t)r0 << 9) + co4;

    auto body = [&](int rr, const float4* wv) {
        const float cwv = FIRST ? (1.0f / (float)R_) : cwl[rr * 16 + c];
        #pragma unroll
        for (int j = 0; j < 4; ++j) {
            const float4 xa = xl4[(b4 * 4 + j) * (RCH_ * 2) + rr * 2];
            const float4 xb = xl4[(b4 * 4 + j) * (RCH_ * 2) + rr * 2 + 1];
            const float d0 = wv[0].x*xa.x + wv[0].y*xa.y + wv[0].z*xa.z + wv[0].w*xa.w
                           + wv[1].x*xb.x + wv[1].y*xb.y + wv[1].z*xb.z + wv[1].w*xb.w;
            const float d1 = wv[2].x*xa.x + wv[2].y*xa.y + wv[2].z*xa.z + wv[2].w*xa.w
                           + wv[3].x*xb.x + wv[3].y*xb.y + wv[3].z*xb.z + wv[3].w*xb.w;
            const float d2 = wv[4].x*xa.x + wv[4].y*xa.y + wv[4].z*xa.z + wv[4].w*xa.w
                           + wv[5].x*xb.x + wv[5].y*xb.y + wv[5].z*xb.z + wv[5].w*xb.w;
            const float d3 = wv[6].x*xa.x + wv[6].y*xa.y + wv[6].z*xa.z + wv[6].w*xa.w
                           + wv[7].x*xb.x + wv[7].y*xb.y + wv[7].z*xb.z + wv[7].w*xb.w;
            acc[j][0] = fmaf(cwv, d0, acc[j][0]);
            acc[j][1] = fmaf(cwv, d1, acc[j][1]);
            acc[j][2] = fmaf(cwv, d2, acc[j][2]);
            acc[j][3] = fmaf(cwv, d3, acc[j][3]);
        }
    };

    // software-pipelined K loop: prefetch next rr's 8 W-fragments into regs
    float4 w[8];
    #pragma unroll
    for (int q = 0; q < 8; ++q) w[q] = wbase[q * 64];
    for (int rr = 0; rr < RCH_ - 1; ++rr) {
        float4 wn[8];
        const float4* wp = wbase + ((size_t)(rr + 1) << 9);
        #pragma unroll
        for (int q = 0; q < 8; ++q) wn[q] = wp[q * 64];
        body(rr, w);
        #pragma unroll
        for (int q = 0; q < 8; ++q) w[q] = wn[q];
    }
    body(RCH_ - 1, w);

    // write partials (fully coalesced; slice pitch non-pow2)
    float4* sp4 = (float4*)sp;
    #pragma unroll
    for (int j = 0; j < 4; ++j) {
        const int b = bt * 16 + b4 * 4 + j;
        float4 o4; o4.x = acc[j][0]; o4.y = acc[j][1]; o4.z = acc[j][2]; o4.w = acc[j][3];
        sp4[(size_t)rs * SLICE_P + b * 64 + co4] = o4;
    }
}

// ---------- R: v[b,co] = squash(sum_k sp[k][b][co]) -----------------------
// grid 32 x 256: one thread per output float4, k-walk fully sequential per
// thread, wave-coalesced (64 lanes = 1 KB lines), channel-rotating pitch.
__global__ __launch_bounds__(256) void reduce_squash_k(const float* __restrict__ sp,
                                                       float* __restrict__ dst) {
    const int out4 = blockIdx.x * 256 + threadIdx.x;
    const float4* __restrict__ sp4 = (const float4*)sp;
    float ax = 0.f, ay = 0.f, az = 0.f, aw = 0.f;
    #pragma unroll 16
    for (int k = 0; k < RS_; ++k) {
        const float4 u = sp4[(size_t)k * SLICE_P + out4];
        ax += u.x; ay += u.y; az += u.z; aw += u.w;
    }
    float4 o;
    o.x = squashf(ax); o.y = squashf(ay); o.z = squashf(az); o.w = squashf(aw);
    ((float4*)dst)[out4] = o;
}

// ---------- A: blog[r,c] (+)= (1/B) sum_{b,o} u_hat[b,r,co]*v[b,co]
// grid 1152 x 256 (1 r per block, 4 waves = batch quarters). Also accumulates
// colsum[c*16] += exp(new_blog) (one cache line per c -> parallel atomics).
template <bool FIRST>
__global__ __launch_bounds__(256, 4) void a_k(const float* __restrict__ x,
                                              const float* __restrict__ wt,
                                              const float* __restrict__ v,
                                              float* __restrict__ blog,
                                              float* __restrict__ colsum) {
    const int r = blockIdx.x;
    const int t = threadIdx.x;
    const int w = t >> 6, lane = t & 63;
    const int co4 = lane, c = lane >> 2;

    __shared__ float4 xl[256];            // 128 b x 2 f4 = 4 KB
    __shared__ float  red[64];
    const float4* __restrict__ X4  = (const float4*)x;
    const float4* __restrict__ V4  = (const float4*)v;
    const float4* __restrict__ Wt4 = (const float4*)wt;

    {
        const int b = t >> 1, rem = t & 1;
        xl[t] = X4[(b * R_ + r) * 2 + rem];
    }
    __syncthreads();

    float y[8][4];
    #pragma unroll
    for (int i = 0; i < 8; ++i)
        #pragma unroll
        for (int q = 0; q < 4; ++q) y[i][q] = 0.f;

    const int b0 = w * 32;
    #pragma unroll 4
    for (int bb = 0; bb < 32; ++bb) {
        const int b = b0 + bb;
        const float4 xa = xl[b * 2];
        const float4 xb = xl[b * 2 + 1];
        const float4 vv = V4[b * 64 + co4];
        const float xs[8] = {xa.x, xa.y, xa.z, xa.w, xb.x, xb.y, xb.z, xb.w};
        #pragma unroll
        for (int i = 0; i < 8; ++i) {
            y[i][0] = fmaf(xs[i], vv.x, y[i][0]);
            y[i][1] = fmaf(xs[i], vv.y, y[i][1]);
            y[i][2] = fmaf(xs[i], vv.z, y[i][2]);
            y[i][3] = fmaf(xs[i], vv.w, y[i][3]);
        }
    }

    const float4* wp = Wt4 + ((size_t)r << 9) + co4;
    float part = 0.f;
    #pragma unroll
    for (int q = 0; q < 4; ++q) {
        const float4 w0 = wp[(2 * q) * 64];
        const float4 w1 = wp[(2 * q + 1) * 64];
        part += w0.x*y[0][q] + w0.y*y[1][q] + w0.z*y[2][q] + w0.w*y[3][q]
              + w1.x*y[4][q] + w1.y*y[5][q] + w1.z*y[6][q] + w1.w*y[7][q];
    }
    part += __shfl_xor(part, 1);
    part += __shfl_xor(part, 2);
    if ((lane & 3) == 0) red[w * 16 + c] = part;
    __syncthreads();
    if (t < 16) {
        const float val = ((red[t] + red[16 + t]) + (red[32 + t] + red[48 + t]))
                          * (1.0f / (float)B_);
        const int idx = r * 16 + t;
        const float nv = FIRST ? val : (blog[idx] + val);
        blog[idx] = nv;
        atomicAdd(&colsum[t * 16], __expf(nv));   // softmax denominator for next gemm
    }
}

extern "C" void kernel_launch(void* const* d_in, const int* in_sizes, int n_in,
                              void* d_out, int out_size, void* d_ws, size_t ws_size,
                              hipStream_t stream) {
    const float* x = (const float*)d_in[0];   // [128,1152,8]
    const float* W = (const float*)d_in[1];   // [1,1152,16,16,8]
    float* out = (float*)d_out;               // [128,16,16]
    float* ws  = (float*)d_ws;                // ~22.6 MB used

    float* sp   = ws + WS_SP;
    float* v    = ws + WS_V;
    float* blog = ws + WS_BLOG;
    float* ctrl = ws + WS_CTRL;
    float* wt   = ws + WS_WT;

    float* cs0 = ctrl + 256;                  // 16 counters, stride 16 floats (64 B)
    float* cs1 = ctrl + 512;

    // build Wt once (coalesced transpose) + zero colsums
    wtrans_k<<<R_, 512, 0, stream>>>(W, wt, ctrl);

    // iter 0 (softmax(0) == 1/R exactly)
    gemm_s_k<true ><<<NBLK, 256, 0, stream>>>(x, wt, nullptr, nullptr, sp);
    reduce_squash_k<<<32, 256, 0, stream>>>(sp, v);
    a_k<true ><<<R_, 256, 0, stream>>>(x, wt, v, blog, cs0);

    // iter 1
    gemm_s_k<false><<<NBLK, 256, 0, stream>>>(x, wt, blog, cs0, sp);
    reduce_squash_k<<<32, 256, 0, stream>>>(sp, v);
    a_k<false><<<R_, 256, 0, stream>>>(x, wt, v, blog, cs1);

    // iter 2 — reduce writes squash(s) directly to out
    gemm_s_k<false><<<NBLK, 256, 0, stream>>>(x, wt, blog, cs1, sp);
    reduce_squash_k<<<32, 256, 0, stream>>>(sp, out);
}